// Round 1
// baseline (74.361 us; speedup 1.0000x reference)
//
#include <hip/hip_runtime.h>

// Problem shape (fixed by the reference): X [B=8, L=4096, D=1024] fp32.
// O = (L*X - colsum_over_L) / (L-1).
constexpr int Bn = 8;
constexpr int Ln = 4096;
constexpr int Dn = 1024;

constexpr int TD  = 32;          // d-columns per block  -> 32 tiles/batch
constexpr int NT  = 1024;        // threads per block (16 waves/CU)
constexpr int QPB = TD / 4;      // 8 float4-quads span one row of the tile
constexpr int RPI = NT / QPB;    // 128 rows covered per loop iteration
constexpr int NIT = Ln / RPI;    // 32 iterations over L

__global__ __launch_bounds__(NT) void ordering_fused_kernel(
    const float* __restrict__ X, float* __restrict__ O) {
    const int tid  = threadIdx.x;
    const int b    = blockIdx.x >> 5;    // / 32 tiles
    const int tile = blockIdx.x & 31;
    const int d0   = tile * TD;
    const int q    = tid & (QPB - 1);    // which float4 within the 32-col tile
    const int g    = tid >> 3;           // row group 0..127

    // element offset of this thread's column-quad in batch b, row 0
    const size_t base = (size_t)b * Ln * Dn + (size_t)d0 + (size_t)q * 4;

    // ---- Phase 1: column partial sums over L ----
    float4 acc = make_float4(0.f, 0.f, 0.f, 0.f);
#pragma unroll 8
    for (int it = 0; it < NIT; ++it) {
        const int row = it * RPI + g;
        const float4 v =
            *reinterpret_cast<const float4*>(X + base + (size_t)row * Dn);
        acc.x += v.x; acc.y += v.y; acc.z += v.z; acc.w += v.w;
    }

    // ---- LDS tree reduce across the 128 row-groups (fixed order: deterministic)
    __shared__ float4 red[NT];   // 16 KiB
    red[tid] = acc;
    __syncthreads();
#pragma unroll
    for (int s = NT / 2; s >= QPB; s >>= 1) {
        if (tid < s) {
            float4 a = red[tid];
            const float4 o = red[tid + s];
            a.x += o.x; a.y += o.y; a.z += o.z; a.w += o.w;
            red[tid] = a;
        }
        __syncthreads();
    }
    const float4 tot = red[q];   // broadcast read (same-address: conflict-free)

    // ---- Phase 2: O = (L*x - tot) / (L-1); re-read should hit L2/L3 ----
    const float Lf  = (float)Ln;
    const float inv = 1.0f / (float)(Ln - 1);
#pragma unroll 4
    for (int it = 0; it < NIT; ++it) {
        const int row = it * RPI + g;
        const size_t off = base + (size_t)row * Dn;
        const float4 v = *reinterpret_cast<const float4*>(X + off);
        float4 o;
        o.x = (Lf * v.x - tot.x) * inv;
        o.y = (Lf * v.y - tot.y) * inv;
        o.z = (Lf * v.z - tot.z) * inv;
        o.w = (Lf * v.w - tot.w) * inv;
        *reinterpret_cast<float4*>(O + off) = o;
    }
}

extern "C" void kernel_launch(void* const* d_in, const int* in_sizes, int n_in,
                              void* d_out, int out_size, void* d_ws, size_t ws_size,
                              hipStream_t stream) {
    (void)in_sizes; (void)n_in; (void)d_ws; (void)ws_size; (void)out_size;
    const float* X = (const float*)d_in[0];
    float* O = (float*)d_out;
    const int grid = Bn * (Dn / TD);   // 256 blocks
    ordering_fused_kernel<<<grid, NT, 0, stream>>>(X, O);
}

// Round 3
// 64.418 us; speedup vs baseline: 1.1544x; 1.1544x over previous
//
#include <hip/hip_runtime.h>

// X [B=8, L=4096, D=1024] fp32.  O = (L*X - colsum_over_L) / (L-1).
constexpr int Bn = 8;
constexpr int Ln = 4096;
constexpr int Dn = 1024;

constexpr int TD  = 32;          // d-columns per block  -> 32 tiles/batch, 256 blocks
constexpr int NT  = 1024;        // threads per block (16 waves)
constexpr int QPB = TD / 4;      // 8 float4-quads span one row of the tile
constexpr int RPI = NT / QPB;    // 128 rows covered per loop iteration
constexpr int NIT = Ln / RPI;    // 32 iterations over L
constexpr int NW  = NT / 64;     // 16 waves

typedef float f32x4 __attribute__((ext_vector_type(4)));

__global__ __launch_bounds__(NT) void ordering_fused_kernel(
    const float* __restrict__ X, float* __restrict__ O) {
    const int tid  = threadIdx.x;
    const int lane = tid & 63;
    const int w    = tid >> 6;           // wave id 0..15
    const int b    = blockIdx.x >> 5;
    const int tile = blockIdx.x & 31;
    const int d0   = tile * TD;
    const int q    = tid & (QPB - 1);    // float4-quad within the 32-col tile
    const int g    = tid >> 3;           // row group 0..127

    const size_t base = (size_t)b * Ln * Dn + (size_t)d0 + (size_t)q * 4;

    // ---- Phase 1: column partial sums over L (4 independent accumulators) ----
    f32x4 a0 = (f32x4)0.f, a1 = (f32x4)0.f, a2 = (f32x4)0.f, a3 = (f32x4)0.f;
#pragma unroll
    for (int it = 0; it < NIT; it += 4) {
        const f32x4 v0 = *reinterpret_cast<const f32x4*>(X + base + (size_t)((it+0)*RPI + g) * Dn);
        const f32x4 v1 = *reinterpret_cast<const f32x4*>(X + base + (size_t)((it+1)*RPI + g) * Dn);
        const f32x4 v2 = *reinterpret_cast<const f32x4*>(X + base + (size_t)((it+2)*RPI + g) * Dn);
        const f32x4 v3 = *reinterpret_cast<const f32x4*>(X + base + (size_t)((it+3)*RPI + g) * Dn);
        a0 += v0; a1 += v1; a2 += v2; a3 += v3;
    }
    f32x4 acc = (a0 + a1) + (a2 + a3);

    // ---- Wave-level butterfly over the 8 row-groups within each wave ----
    // lane = q + 8*(group-within-wave); xor masks 8,16,32 sum the groups.
#pragma unroll
    for (int m = 8; m <= 32; m <<= 1) {
        f32x4 o;
        o.x = __shfl_xor(acc.x, m);
        o.y = __shfl_xor(acc.y, m);
        o.z = __shfl_xor(acc.z, m);
        o.w = __shfl_xor(acc.w, m);
        acc += o;
    }

    // ---- Cross-wave: 16 waves x 8 quads, one barrier, fixed-order sum ----
    __shared__ f32x4 red[NW * QPB];   // 2 KiB
    if (lane < QPB) red[w * QPB + q] = acc;
    __syncthreads();
    f32x4 tot = (f32x4)0.f;
#pragma unroll
    for (int ww = 0; ww < NW; ++ww) {
        tot += red[ww * QPB + q];   // broadcast read per q
    }

    // ---- Phase 2: O = (L*x - tot)/(L-1); X re-read hits L2/L3; NT stores ----
    const float Lf  = (float)Ln;
    const float inv = 1.0f / (float)(Ln - 1);
#pragma unroll 8
    for (int it = 0; it < NIT; ++it) {
        const size_t off = base + (size_t)(it * RPI + g) * Dn;
        const f32x4 v = *reinterpret_cast<const f32x4*>(X + off);
        const f32x4 o = (Lf * v - tot) * inv;
        __builtin_nontemporal_store(o, reinterpret_cast<f32x4*>(O + off));
    }
}

extern "C" void kernel_launch(void* const* d_in, const int* in_sizes, int n_in,
                              void* d_out, int out_size, void* d_ws, size_t ws_size,
                              hipStream_t stream) {
    (void)in_sizes; (void)n_in; (void)d_ws; (void)ws_size; (void)out_size;
    const float* X = (const float*)d_in[0];
    float* O = (float*)d_out;
    const int grid = Bn * (Dn / TD);   // 256 blocks
    ordering_fused_kernel<<<grid, NT, 0, stream>>>(X, O);
}